// Round 1
// baseline (10365.641 us; speedup 1.0000x reference)
//
#include <hip/hip_runtime.h>
#include <hip/hip_bf16.h>
#include <math.h>

// MeanShifter: 3 x { q = x@Wq+bq; attn = softmax(q q^T / 8); x = LN(attn @ x) }
// B=8, N=2304, D=768, Dm=64. fp32 baseline, flash-style (no S matrix).

#define BB 8
#define NN 2304
#define DD 768
#define DM 64
#define TM 32      // query rows per block
#define TK 64      // key tile
#define EPSF 1e-5f

// ---------------- Q projection: q[b,n,m] = sum_d x[b,n,d] * Wq[d,m] + bq[m] ----
// block = 256 threads = 4 rows x 64 m-lanes
__global__ void proj_kernel(const float* __restrict__ x, const float* __restrict__ Wq,
                            const float* __restrict__ bq, float* __restrict__ q) {
    int t = threadIdx.x;
    int m = t & 63;
    int rl = t >> 6;
    long row = (long)blockIdx.x * 4 + rl;   // 0..B*N-1
    const float* xr = x + row * DD;
    float acc = bq[m];
    #pragma unroll 4
    for (int d = 0; d < DD; d += 4) {
        float4 xv = *(const float4*)(xr + d);
        acc += xv.x * Wq[(d + 0) * DM + m];
        acc += xv.y * Wq[(d + 1) * DM + m];
        acc += xv.z * Wq[(d + 2) * DM + m];
        acc += xv.w * Wq[(d + 3) * DM + m];
    }
    q[row * DM + m] = acc;
}

// ---------------- fused flash-attention + LayerNorm --------------------------
// grid: (N/TM, B), block 256. Each block: TM query rows, all 768 output dims.
// Thread t owns cols {t, t+256, t+512} for ALL TM rows -> o[TM][3] regs.
__global__ void attn_ln_kernel(const float* __restrict__ x, const float* __restrict__ q,
                               const float* __restrict__ gamma, const float* __restrict__ beta,
                               float* __restrict__ out) {
    __shared__ float qL[TM][68];        // queries, pad 68 (16B-aligned rows)
    __shared__ float pL[TK][36];        // scores/probs [k][r], pad 36
    __shared__ float mL[TM], lL[TM], aL[TM];
    __shared__ float muL[TM], rsL[TM];
    __shared__ float redA[4][TM], redB[4][TM];

    int t = threadIdx.x;
    int b = blockIdx.y;
    int n0 = blockIdx.x * TM;
    const float* qb = q + (long)b * NN * DM;
    const float* xb = x + (long)b * NN * DD;

    // stage queries
    for (int i = t; i < TM * DM; i += 256) {
        int r = i >> 6, d = i & 63;
        qL[r][d] = qb[(long)(n0 + r) * DM + d];
    }
    if (t < TM) { mL[t] = -1e30f; lL[t] = 0.f; }

    float o[TM][3];
    #pragma unroll
    for (int r = 0; r < TM; ++r) { o[r][0] = 0.f; o[r][1] = 0.f; o[r][2] = 0.f; }

    const int c0 = t, c1 = t + 256, c2 = t + 512;
    float g0 = gamma[c0], g1 = gamma[c1], g2 = gamma[c2];
    float be0 = beta[c0], be1 = beta[c1], be2 = beta[c2];

    const int r = t & 31;    // score-phase row
    const int kg = t >> 5;   // score-phase k group (0..7)
    __syncthreads();

    for (int k0 = 0; k0 < NN; k0 += TK) {
        // --- scores: s[r][kk] = (qL[r] . q[k0+kk]) / 8 ---
        float s[8];
        #pragma unroll
        for (int jj = 0; jj < 8; ++jj) {
            int kk = kg * 8 + jj;
            const float* kr = qb + (long)(k0 + kk) * DM;
            float acc = 0.f;
            #pragma unroll
            for (int d = 0; d < DM; d += 4) {
                float4 kv = *(const float4*)(kr + d);
                float4 qv = *(const float4*)&qL[r][d];
                acc += kv.x * qv.x + kv.y * qv.y + kv.z * qv.z + kv.w * qv.w;
            }
            s[jj] = acc * 0.125f;
            pL[kk][r] = s[jj];
        }
        __syncthreads();
        // --- per-row running max & rescale factor ---
        if (t < TM) {
            float mx = -1e30f;
            #pragma unroll
            for (int kk = 0; kk < TK; ++kk) mx = fmaxf(mx, pL[kk][t]);
            float mold = mL[t];
            float mnew = fmaxf(mold, mx);
            aL[t] = __expf(mold - mnew);
            mL[t] = mnew;
        }
        __syncthreads();
        // --- exponentiate ---
        float mrow = mL[r];
        #pragma unroll
        for (int jj = 0; jj < 8; ++jj) {
            int kk = kg * 8 + jj;
            pL[kk][r] = __expf(s[jj] - mrow);
        }
        __syncthreads();
        // --- l update (row threads) ---
        if (t < TM) {
            float sum = 0.f;
            #pragma unroll
            for (int kk = 0; kk < TK; ++kk) sum += pL[kk][t];
            lL[t] = lL[t] * aL[t] + sum;
        }
        // --- rescale accumulator ---
        #pragma unroll
        for (int rr = 0; rr < TM; ++rr) {
            float a = aL[rr];
            o[rr][0] *= a; o[rr][1] *= a; o[rr][2] *= a;
        }
        // --- accumulate o += P @ x_tile ---
        for (int kk = 0; kk < TK; ++kk) {
            const float* xr = xb + (long)(k0 + kk) * DD;
            float xv0 = xr[c0], xv1 = xr[c1], xv2 = xr[c2];
            #pragma unroll
            for (int r4 = 0; r4 < TM; r4 += 4) {
                float4 pv = *(const float4*)&pL[kk][r4];
                o[r4 + 0][0] += pv.x * xv0; o[r4 + 0][1] += pv.x * xv1; o[r4 + 0][2] += pv.x * xv2;
                o[r4 + 1][0] += pv.y * xv0; o[r4 + 1][1] += pv.y * xv1; o[r4 + 1][2] += pv.y * xv2;
                o[r4 + 2][0] += pv.z * xv0; o[r4 + 2][1] += pv.z * xv1; o[r4 + 2][2] += pv.z * xv2;
                o[r4 + 3][0] += pv.w * xv0; o[r4 + 3][1] += pv.w * xv1; o[r4 + 3][2] += pv.w * xv2;
            }
        }
        __syncthreads();   // protect pL/aL/lL before next tile
    }

    // --- softmax denominator ---
    if (t < TM) lL[t] = 1.f / lL[t];
    __syncthreads();
    #pragma unroll
    for (int rr = 0; rr < TM; ++rr) {
        float il = lL[rr];
        o[rr][0] *= il; o[rr][1] *= il; o[rr][2] *= il;
    }

    // --- LayerNorm: per-row mean/var over 768 cols (spread across 256 threads) ---
    int w = t >> 6, lane = t & 63;
    #pragma unroll
    for (int rr = 0; rr < TM; ++rr) {
        float s1 = o[rr][0] + o[rr][1] + o[rr][2];
        float s2 = o[rr][0] * o[rr][0] + o[rr][1] * o[rr][1] + o[rr][2] * o[rr][2];
        for (int off = 32; off; off >>= 1) {
            s1 += __shfl_down(s1, off);
            s2 += __shfl_down(s2, off);
        }
        if (lane == 0) { redA[w][rr] = s1; redB[w][rr] = s2; }
    }
    __syncthreads();
    if (t < TM) {
        float sA = redA[0][t] + redA[1][t] + redA[2][t] + redA[3][t];
        float sB = redB[0][t] + redB[1][t] + redB[2][t] + redB[3][t];
        float mu = sA * (1.f / 768.f);
        float var = sB * (1.f / 768.f) - mu * mu;
        muL[t] = mu;
        rsL[t] = rsqrtf(var + EPSF);
    }
    __syncthreads();
    float* ob = out + (long)b * NN * DD;
    #pragma unroll
    for (int rr = 0; rr < TM; ++rr) {
        float mu = muL[rr], rs = rsL[rr];
        float* orow = ob + (long)(n0 + rr) * DD;
        orow[c0] = (o[rr][0] - mu) * rs * g0 + be0;
        orow[c1] = (o[rr][1] - mu) * rs * g1 + be1;
        orow[c2] = (o[rr][2] - mu) * rs * g2 + be2;
    }
}

extern "C" void kernel_launch(void* const* d_in, const int* in_sizes, int n_in,
                              void* d_out, int out_size, void* d_ws, size_t ws_size,
                              hipStream_t stream) {
    (void)in_sizes; (void)n_in; (void)out_size; (void)ws_size;
    const float* x     = (const float*)d_in[0];
    const float* Wq    = (const float*)d_in[1];
    const float* bq    = (const float*)d_in[2];
    const float* gamma = (const float*)d_in[3];
    const float* beta  = (const float*)d_in[4];
    float* out  = (float*)d_out;
    float* bufA = (float*)d_ws;                                   // 56.6 MB
    float* qbuf = (float*)((char*)d_ws + (size_t)BB * NN * DD * 4); // 4.7 MB

    dim3 gProj(BB * NN / 4);
    dim3 gAttn(NN / TM, BB);

    // layer 0: x(in) -> out
    proj_kernel<<<gProj, 256, 0, stream>>>(x, Wq, bq, qbuf);
    attn_ln_kernel<<<gAttn, 256, 0, stream>>>(x, qbuf, gamma, beta, out);
    // layer 1: out -> bufA
    proj_kernel<<<gProj, 256, 0, stream>>>(out, Wq, bq, qbuf);
    attn_ln_kernel<<<gAttn, 256, 0, stream>>>(out, qbuf, gamma, beta, bufA);
    // layer 2: bufA -> out
    proj_kernel<<<gProj, 256, 0, stream>>>(bufA, Wq, bq, qbuf);
    attn_ln_kernel<<<gAttn, 256, 0, stream>>>(bufA, qbuf, gamma, beta, out);
}

// Round 3
// 3453.347 us; speedup vs baseline: 3.0016x; 3.0016x over previous
//
#include <hip/hip_runtime.h>
#include <math.h>

#define BB 8
#define NN 2304
#define DD 768
#define DM 64
#define EPSF 1e-5f

typedef __attribute__((ext_vector_type(8))) short short8;   // 8 x bf16 bits
typedef __attribute__((ext_vector_type(4))) float f32x4;

static __device__ __forceinline__ unsigned short f2b(float f) {
    unsigned u = __float_as_uint(f);
    unsigned r = u + 0x7FFFu + ((u >> 16) & 1u);
    return (unsigned short)(r >> 16);
}
static __device__ __forceinline__ float b2f(unsigned short h) {
    return __uint_as_float(((unsigned)h) << 16);
}

// ---------- layer-0: fp32 x -> split-bf16 transposed xT_hi/xT_lo [B][D][N] ------
__global__ __launch_bounds__(256) void cvt_kernel(const float* __restrict__ xf,
                                                  unsigned short* __restrict__ xTh,
                                                  unsigned short* __restrict__ xTl) {
    __shared__ __align__(16) unsigned short Th[64][72];
    __shared__ __align__(16) unsigned short Tl[64][72];
    int t = threadIdx.x;
    int b = blockIdx.z;
    int n0 = blockIdx.x * 64, c0 = blockIdx.y * 64;
    int rr = t >> 4, cc = (t & 15) * 4;
    #pragma unroll
    for (int i = 0; i < 4; ++i) {
        int r = rr + i * 16;
        long idx = ((long)b * NN + n0 + r) * DD + c0 + cc;
        float4 v = *(const float4*)&xf[idx];
        unsigned short h0 = f2b(v.x), h1 = f2b(v.y), h2 = f2b(v.z), h3 = f2b(v.w);
        Th[cc + 0][r] = h0; Th[cc + 1][r] = h1; Th[cc + 2][r] = h2; Th[cc + 3][r] = h3;
        Tl[cc + 0][r] = f2b(v.x - b2f(h0));
        Tl[cc + 1][r] = f2b(v.y - b2f(h1));
        Tl[cc + 2][r] = f2b(v.z - b2f(h2));
        Tl[cc + 3][r] = f2b(v.w - b2f(h3));
    }
    __syncthreads();
    #pragma unroll
    for (int i = 0; i < 4; ++i) {
        int c = rr + i * 16;
        long idx = ((long)b * DD + c0 + c) * NN + n0 + cc;
        *(ushort4*)&xTh[idx] = *(const ushort4*)&Th[c][cc];
        *(ushort4*)&xTl[idx] = *(const ushort4*)&Tl[c][cc];
    }
}

// ---------- q projection (fp32 math): q = x@Wq + bq, stored split hi/lo ---------
__global__ __launch_bounds__(256) void proj_kernel(const float* __restrict__ x,
                                                   const float* __restrict__ Wq,
                                                   const float* __restrict__ bq,
                                                   unsigned short* __restrict__ qh,
                                                   unsigned short* __restrict__ ql) {
    int t = threadIdx.x;
    int m = t & 63, rl = t >> 6;
    long row = (long)blockIdx.x * 4 + rl;
    const float* xr = x + row * DD;
    float acc = bq[m];
    #pragma unroll 4
    for (int d = 0; d < DD; d += 4) {
        float4 xv = *(const float4*)(xr + d);
        acc += xv.x * Wq[(d + 0) * DM + m];
        acc += xv.y * Wq[(d + 1) * DM + m];
        acc += xv.z * Wq[(d + 2) * DM + m];
        acc += xv.w * Wq[(d + 3) * DM + m];
    }
    unsigned short h = f2b(acc);
    qh[row * DM + m] = h;
    ql[row * DM + m] = f2b(acc - b2f(h));
}

// ---------- fused flash attention (no-max softmax, split precision) + LN --------
// grid (N/32, B), block 256 = 4 waves. Block: 32 query rows x all 768 cols.
__global__ __launch_bounds__(256) void attn_ln_kernel(
        const unsigned short* __restrict__ qhp, const unsigned short* __restrict__ qlp,
        const unsigned short* __restrict__ xTh, const unsigned short* __restrict__ xTl,
        const float* __restrict__ gamma, const float* __restrict__ beta,
        float* __restrict__ outf,
        unsigned short* __restrict__ xTnh, unsigned short* __restrict__ xTnl) {
    __shared__ __align__(16) unsigned short Plds[32 * 72];
    __shared__ float lsum[2][32];
    __shared__ float part1[4][32], part2[4][32];

    const int t = threadIdx.x;
    const int w = t >> 6, lane = t & 63, quad = lane >> 4, l15 = lane & 15;
    const int b = blockIdx.y, n0 = blockIdx.x * 32;
    const int rt = w & 1, kt2 = (w >> 1) * 2;
    const int cbase = w * 192;

    const unsigned short* qhb = qhp + (long)b * NN * DM;
    const unsigned short* qlb = qlp + (long)b * NN * DM;
    const unsigned short* xThb = xTh + (long)b * DD * NN;
    const unsigned short* xTlb = xTl + (long)b * DD * NN;

    // loop-invariant S A-frags (query rows), hi and lo
    short8 aS0h, aS1h, aS0l, aS1l;
    {
        long off = (long)(n0 + rt * 16 + l15) * DM + quad * 8;
        aS0h = *(const short8*)(qhb + off);
        aS1h = *(const short8*)(qhb + off + 32);
        aS0l = *(const short8*)(qlb + off);
        aS1l = *(const short8*)(qlb + off + 32);
    }

    float l_part[4] = {0.f, 0.f, 0.f, 0.f};
    f32x4 acc[12][2];
    #pragma unroll
    for (int i = 0; i < 12; ++i) { acc[i][0] = 0.f; acc[i][1] = 0.f; }

    for (int k0 = 0; k0 < NN; k0 += 64) {
        // ---- S tiles: keys kt2*16+l15 (sA) and +16 (sB), split-precision ----
        f32x4 sA = 0.f, sB = 0.f;
        {
            long off0 = (long)(k0 + kt2 * 16 + l15) * DM + quad * 8;
            long off1 = off0 + 16 * DM;
            short8 b00h = *(const short8*)(qhb + off0);
            short8 b01h = *(const short8*)(qhb + off0 + 32);
            short8 b10h = *(const short8*)(qhb + off1);
            short8 b11h = *(const short8*)(qhb + off1 + 32);
            short8 b00l = *(const short8*)(qlb + off0);
            short8 b01l = *(const short8*)(qlb + off0 + 32);
            short8 b10l = *(const short8*)(qlb + off1);
            short8 b11l = *(const short8*)(qlb + off1 + 32);
            sA = __builtin_amdgcn_mfma_f32_16x16x32_bf16(aS0h, b00h, sA, 0, 0, 0);
            sA = __builtin_amdgcn_mfma_f32_16x16x32_bf16(aS1h, b01h, sA, 0, 0, 0);
            sA = __builtin_amdgcn_mfma_f32_16x16x32_bf16(aS0l, b00h, sA, 0, 0, 0);
            sA = __builtin_amdgcn_mfma_f32_16x16x32_bf16(aS1l, b01h, sA, 0, 0, 0);
            sA = __builtin_amdgcn_mfma_f32_16x16x32_bf16(aS0h, b00l, sA, 0, 0, 0);
            sA = __builtin_amdgcn_mfma_f32_16x16x32_bf16(aS1h, b01l, sA, 0, 0, 0);
            sB = __builtin_amdgcn_mfma_f32_16x16x32_bf16(aS0h, b10h, sB, 0, 0, 0);
            sB = __builtin_amdgcn_mfma_f32_16x16x32_bf16(aS1h, b11h, sB, 0, 0, 0);
            sB = __builtin_amdgcn_mfma_f32_16x16x32_bf16(aS0l, b10h, sB, 0, 0, 0);
            sB = __builtin_amdgcn_mfma_f32_16x16x32_bf16(aS1l, b11h, sB, 0, 0, 0);
            sB = __builtin_amdgcn_mfma_f32_16x16x32_bf16(aS0h, b10l, sB, 0, 0, 0);
            sB = __builtin_amdgcn_mfma_f32_16x16x32_bf16(aS1h, b11l, sB, 0, 0, 0);
        }
        const int prow0 = rt * 16 + quad * 4;
        #pragma unroll
        for (int e = 0; e < 4; ++e) {
            float pA = __expf(sA[e] * 0.125f);
            float pB = __expf(sB[e] * 0.125f);
            l_part[e] += pA + pB;
            Plds[(prow0 + e) * 72 + kt2 * 16 + l15] = f2b(pA);
            Plds[(prow0 + e) * 72 + kt2 * 16 + 16 + l15] = f2b(pB);
        }
        __syncthreads();
        // ---- PV: O^T[c][r] += (x_hi + x_lo)-frag @ P-frag ----
        #pragma unroll
        for (int kh = 0; kh < 2; ++kh) {
            short8 pb0 = *(const short8*)&Plds[l15 * 72 + kh * 32 + quad * 8];
            short8 pb1 = *(const short8*)&Plds[(16 + l15) * 72 + kh * 32 + quad * 8];
            long xoff = (long)(cbase + l15) * NN + k0 + kh * 32 + quad * 8;
            #pragma unroll
            for (int ct = 0; ct < 12; ++ct) {
                short8 axh = *(const short8*)(xThb + xoff + (long)ct * 16 * NN);
                short8 axl = *(const short8*)(xTlb + xoff + (long)ct * 16 * NN);
                acc[ct][0] = __builtin_amdgcn_mfma_f32_16x16x32_bf16(axh, pb0, acc[ct][0], 0, 0, 0);
                acc[ct][0] = __builtin_amdgcn_mfma_f32_16x16x32_bf16(axl, pb0, acc[ct][0], 0, 0, 0);
                acc[ct][1] = __builtin_amdgcn_mfma_f32_16x16x32_bf16(axh, pb1, acc[ct][1], 0, 0, 0);
                acc[ct][1] = __builtin_amdgcn_mfma_f32_16x16x32_bf16(axl, pb1, acc[ct][1], 0, 0, 0);
            }
        }
        __syncthreads();
    }

    // ---- softmax denominator ----
    #pragma unroll
    for (int e = 0; e < 4; ++e) {
        float v = l_part[e];
        v += __shfl_xor(v, 1); v += __shfl_xor(v, 2);
        v += __shfl_xor(v, 4); v += __shfl_xor(v, 8);
        if (l15 == 0) lsum[w >> 1][rt * 16 + quad * 4 + e] = v;
    }
    __syncthreads();
    float linv[2];
    linv[0] = 1.f / (lsum[0][l15] + lsum[1][l15]);
    linv[1] = 1.f / (lsum[0][16 + l15] + lsum[1][16 + l15]);

    // ---- LN stats ----
    float s1[2] = {0.f, 0.f}, s2[2] = {0.f, 0.f};
    #pragma unroll
    for (int nt = 0; nt < 2; ++nt)
        #pragma unroll
        for (int ct = 0; ct < 12; ++ct)
            #pragma unroll
            for (int e = 0; e < 4; ++e) {
                float v = acc[ct][nt][e] * linv[nt];
                acc[ct][nt][e] = v;
                s1[nt] += v; s2[nt] += v * v;
            }
    #pragma unroll
    for (int nt = 0; nt < 2; ++nt) {
        s1[nt] += __shfl_xor(s1[nt], 16); s1[nt] += __shfl_xor(s1[nt], 32);
        s2[nt] += __shfl_xor(s2[nt], 16); s2[nt] += __shfl_xor(s2[nt], 32);
    }
    if (quad == 0) {
        part1[w][l15] = s1[0]; part1[w][16 + l15] = s1[1];
        part2[w][l15] = s2[0]; part2[w][16 + l15] = s2[1];
    }
    __syncthreads();
    float mu[2], rs[2];
    #pragma unroll
    for (int nt = 0; nt < 2; ++nt) {
        int r = nt * 16 + l15;
        float m1 = part1[0][r] + part1[1][r] + part1[2][r] + part1[3][r];
        float m2 = part2[0][r] + part2[1][r] + part2[2][r] + part2[3][r];
        float m = m1 * (1.f / 768.f);
        mu[nt] = m;
        rs[nt] = rsqrtf(m2 * (1.f / 768.f) - m * m + EPSF);
    }

    // ---- LN apply + stores: fp32 out, split-bf16 transposed for next layer ----
    float* ob = outf + (long)b * NN * DD;
    unsigned short* xThn = xTnh + (long)b * DD * NN;
    unsigned short* xTln = xTnl + (long)b * DD * NN;
    #pragma unroll
    for (int ct = 0; ct < 12; ++ct) {
        int c0 = cbase + ct * 16 + quad * 4;
        float4 g = *(const float4*)&gamma[c0];
        float4 be = *(const float4*)&beta[c0];
        #pragma unroll
        for (int nt = 0; nt < 2; ++nt) {
            int row = n0 + nt * 16 + l15;
            float o0 = (acc[ct][nt][0] - mu[nt]) * rs[nt] * g.x + be.x;
            float o1 = (acc[ct][nt][1] - mu[nt]) * rs[nt] * g.y + be.y;
            float o2 = (acc[ct][nt][2] - mu[nt]) * rs[nt] * g.z + be.z;
            float o3 = (acc[ct][nt][3] - mu[nt]) * rs[nt] * g.w + be.w;
            float4 ov = { o0, o1, o2, o3 };
            *(float4*)&ob[(long)row * DD + c0] = ov;
            unsigned short h0 = f2b(o0), h1 = f2b(o1), h2 = f2b(o2), h3 = f2b(o3);
            xThn[(long)(c0 + 0) * NN + row] = h0;
            xThn[(long)(c0 + 1) * NN + row] = h1;
            xThn[(long)(c0 + 2) * NN + row] = h2;
            xThn[(long)(c0 + 3) * NN + row] = h3;
            xTln[(long)(c0 + 0) * NN + row] = f2b(o0 - b2f(h0));
            xTln[(long)(c0 + 1) * NN + row] = f2b(o1 - b2f(h1));
            xTln[(long)(c0 + 2) * NN + row] = f2b(o2 - b2f(h2));
            xTln[(long)(c0 + 3) * NN + row] = f2b(o3 - b2f(h3));
        }
    }
}

extern "C" void kernel_launch(void* const* d_in, const int* in_sizes, int n_in,
                              void* d_out, int out_size, void* d_ws, size_t ws_size,
                              hipStream_t stream) {
    (void)in_sizes; (void)n_in; (void)out_size; (void)ws_size;
    const float* x     = (const float*)d_in[0];
    const float* Wq    = (const float*)d_in[1];
    const float* bq    = (const float*)d_in[2];
    const float* gamma = (const float*)d_in[3];
    const float* beta  = (const float*)d_in[4];
    float* out = (float*)d_out;

    char* p = (char*)d_ws;
    const size_t szXT = (size_t)BB * DD * NN * 2;   // 28.3 MB each
    unsigned short* xTAh = (unsigned short*)p; p += szXT;
    unsigned short* xTAl = (unsigned short*)p; p += szXT;
    unsigned short* xTBh = (unsigned short*)p; p += szXT;
    unsigned short* xTBl = (unsigned short*)p; p += szXT;
    unsigned short* qh   = (unsigned short*)p; p += (size_t)BB * NN * DM * 2;
    unsigned short* ql   = (unsigned short*)p; p += (size_t)BB * NN * DM * 2;

    dim3 gCvt(NN / 64, DD / 64, BB);
    dim3 gProj(BB * NN / 4);
    dim3 gAttn(NN / 32, BB);

    cvt_kernel<<<gCvt, 256, 0, stream>>>(x, xTAh, xTAl);
    // layer 0
    proj_kernel<<<gProj, 256, 0, stream>>>(x, Wq, bq, qh, ql);
    attn_ln_kernel<<<gAttn, 256, 0, stream>>>(qh, ql, xTAh, xTAl, gamma, beta, out, xTBh, xTBl);
    // layer 1
    proj_kernel<<<gProj, 256, 0, stream>>>(out, Wq, bq, qh, ql);
    attn_ln_kernel<<<gAttn, 256, 0, stream>>>(qh, ql, xTBh, xTBl, gamma, beta, out, xTAh, xTAl);
    // layer 2
    proj_kernel<<<gProj, 256, 0, stream>>>(out, Wq, bq, qh, ql);
    attn_ln_kernel<<<gAttn, 256, 0, stream>>>(qh, ql, xTAh, xTAl, gamma, beta, out, xTBh, xTBl);
}

// Round 4
// 3005.099 us; speedup vs baseline: 3.4494x; 1.1492x over previous
//
#include <hip/hip_runtime.h>
#include <math.h>

#define BB 8
#define NN 2304
#define DD 768
#define DM 64
#define EPSF 1e-5f

typedef __attribute__((ext_vector_type(8))) short short8;   // 8 x bf16 bits
typedef __attribute__((ext_vector_type(4))) float f32x4;

static __device__ __forceinline__ unsigned short f2b(float f) {
    unsigned u = __float_as_uint(f);
    unsigned r = u + 0x7FFFu + ((u >> 16) & 1u);
    return (unsigned short)(r >> 16);
}
static __device__ __forceinline__ float b2f(unsigned short h) {
    return __uint_as_float(((unsigned)h) << 16);
}
#define MFMA(a, b, c) __builtin_amdgcn_mfma_f32_16x16x32_bf16((a), (b), (c), 0, 0, 0)

// ---------- layer-0: fp32 x [B][N][D] -> split-bf16 transposed xT_hi/lo [B][D][N] ----
__global__ __launch_bounds__(256) void cvt_kernel(const float* __restrict__ xf,
                                                  unsigned short* __restrict__ xTh,
                                                  unsigned short* __restrict__ xTl) {
    __shared__ __align__(16) unsigned short Th[64][72];
    __shared__ __align__(16) unsigned short Tl[64][72];
    int t = threadIdx.x;
    int b = blockIdx.z;
    int n0 = blockIdx.x * 64, c0 = blockIdx.y * 64;
    int rr = t >> 4, cc = (t & 15) * 4;
    #pragma unroll
    for (int i = 0; i < 4; ++i) {
        int r = rr + i * 16;
        long idx = ((long)b * NN + n0 + r) * DD + c0 + cc;
        float4 v = *(const float4*)&xf[idx];
        unsigned short h0 = f2b(v.x), h1 = f2b(v.y), h2 = f2b(v.z), h3 = f2b(v.w);
        Th[cc + 0][r] = h0; Th[cc + 1][r] = h1; Th[cc + 2][r] = h2; Th[cc + 3][r] = h3;
        Tl[cc + 0][r] = f2b(v.x - b2f(h0));
        Tl[cc + 1][r] = f2b(v.y - b2f(h1));
        Tl[cc + 2][r] = f2b(v.z - b2f(h2));
        Tl[cc + 3][r] = f2b(v.w - b2f(h3));
    }
    __syncthreads();
    #pragma unroll
    for (int i = 0; i < 4; ++i) {
        int c = rr + i * 16;
        long idx = ((long)b * DD + c0 + c) * NN + n0 + cc;
        *(ushort4*)&xTh[idx] = *(const ushort4*)&Th[c][cc];
        *(ushort4*)&xTl[idx] = *(const ushort4*)&Tl[c][cc];
    }
}

// ---------- Wq fp32 [768][64] -> transposed split bf16 Wt_hi/lo [64][768] ----------
__global__ __launch_bounds__(256) void wqcvt_kernel(const float* __restrict__ Wq,
                                                    unsigned short* __restrict__ Wth,
                                                    unsigned short* __restrict__ Wtl) {
    int t = blockIdx.x * 256 + threadIdx.x;   // t < 768*64
    int d = t >> 6, m = t & 63;
    float v = Wq[t];
    unsigned short h = f2b(v);
    Wth[m * DD + d] = h;
    Wtl[m * DD + d] = f2b(v - b2f(h));
}

__global__ __launch_bounds__(256) void zstats_kernel(float* __restrict__ stats) {
    stats[blockIdx.x * 256 + threadIdx.x] = 0.f;
}

// ---------- MFMA q-projection: q = (xh+xl)^T-cols @ (Wh+Wl) + bq, split-stored ------
// grid (N/64, B), block 256 = 4 waves; wave w: qm-tile w (16 qm) x 64 rows.
__global__ __launch_bounds__(256) void proj_kernel(
        const unsigned short* __restrict__ Wth, const unsigned short* __restrict__ Wtl,
        const unsigned short* __restrict__ xTh, const unsigned short* __restrict__ xTl,
        const float* __restrict__ bq,
        unsigned short* __restrict__ qh, unsigned short* __restrict__ ql) {
    int t = threadIdx.x;
    int w = t >> 6, lane = t & 63, quad = lane >> 4, l15 = lane & 15;
    int n0 = blockIdx.x * 64, b = blockIdx.y;
    const unsigned short* xhb = xTh + (long)b * DD * NN;
    const unsigned short* xlb = xTl + (long)b * DD * NN;

    f32x4 accQ[4];
    #pragma unroll
    for (int nt = 0; nt < 4; ++nt) accQ[nt] = 0.f;

    for (int d0 = 0; d0 < DD; d0 += 32) {
        short8 ah = *(const short8*)&Wth[(w * 16 + l15) * DD + d0 + quad * 8];
        short8 al = *(const short8*)&Wtl[(w * 16 + l15) * DD + d0 + quad * 8];
        #pragma unroll
        for (int nt = 0; nt < 4; ++nt) {
            int row = n0 + nt * 16 + l15;
            short8 bh, bl;
            #pragma unroll
            for (int j = 0; j < 8; ++j) {
                long o = (long)(d0 + quad * 8 + j) * NN + row;
                bh[j] = (short)xhb[o];
                bl[j] = (short)xlb[o];
            }
            accQ[nt] = MFMA(ah, bh, accQ[nt]);
            accQ[nt] = MFMA(al, bh, accQ[nt]);
            accQ[nt] = MFMA(ah, bl, accQ[nt]);
        }
    }
    #pragma unroll
    for (int nt = 0; nt < 4; ++nt) {
        int row = n0 + nt * 16 + l15;
        #pragma unroll
        for (int e = 0; e < 4; ++e) {
            int qm = w * 16 + quad * 4 + e;
            float v = accQ[nt][e] + bq[qm];
            unsigned short h = f2b(v);
            long o = ((long)b * NN + row) * DM + qm;
            qh[o] = h;
            ql[o] = f2b(v - b2f(h));
        }
    }
}

// ---------- flash attention, barrier-free wave-local, split precision --------------
// grid 1152 = 18 rowtiles x (8 colgroups x 8 batches); blockIdx%8 = batch (XCD affinity).
// Block: 128 q-rows x 96 cols. Wave w: rows [w*32, +32) — S, P, l, PV all wave-private.
__global__ __launch_bounds__(256) void attn_kernel(
        const unsigned short* __restrict__ qhp, const unsigned short* __restrict__ qlp,
        const unsigned short* __restrict__ xTh, const unsigned short* __restrict__ xTl,
        float* __restrict__ OT, float* __restrict__ stats) {
    __shared__ __align__(16) unsigned short Ph[128 * 72];
    __shared__ __align__(16) unsigned short Pl[128 * 72];
    __shared__ float lsum[128];

    const int t = threadIdx.x;
    const int w = t >> 6, lane = t & 63, quad = lane >> 4, l15 = lane & 15;
    const int bx = blockIdx.x;
    const int combo = bx & 63, rt_idx = bx >> 6;
    const int b = combo & 7, g = combo >> 3;
    const int n0 = rt_idx * 128;
    const int rbase = w * 32;         // wave-local row base
    const int cb = g * 96;            // block column base

    const unsigned short* qhb = qhp + (long)b * NN * DM;
    const unsigned short* qlb = qlp + (long)b * NN * DM;
    const unsigned short* xhb = xTh + (long)b * DD * NN;
    const unsigned short* xlb = xTl + (long)b * DD * NN;

    // loop-invariant S A-frags (this wave's 32 query rows, hi/lo, 2 K-chunks)
    short8 ah[2][2], al[2][2];
    #pragma unroll
    for (int rt = 0; rt < 2; ++rt)
        #pragma unroll
        for (int kc = 0; kc < 2; ++kc) {
            long o = (long)(n0 + rbase + rt * 16 + l15) * DM + kc * 32 + quad * 8;
            ah[rt][kc] = *(const short8*)(qhb + o);
            al[rt][kc] = *(const short8*)(qlb + o);
        }

    float lp[2][4];
    #pragma unroll
    for (int rt = 0; rt < 2; ++rt)
        #pragma unroll
        for (int e = 0; e < 4; ++e) lp[rt][e] = 0.f;

    f32x4 acc[6][2];
    #pragma unroll
    for (int ct = 0; ct < 6; ++ct) { acc[ct][0] = 0.f; acc[ct][1] = 0.f; }

    for (int k0 = 0; k0 < NN; k0 += 64) {
        // ---- S + exp + pack P (wave-local LDS rows) ----
        #pragma unroll
        for (int kt = 0; kt < 4; ++kt) {
            long o = (long)(k0 + kt * 16 + l15) * DM + quad * 8;
            short8 bh0 = *(const short8*)(qhb + o);
            short8 bh1 = *(const short8*)(qhb + o + 32);
            short8 bl0 = *(const short8*)(qlb + o);
            short8 bl1 = *(const short8*)(qlb + o + 32);
            #pragma unroll
            for (int rt = 0; rt < 2; ++rt) {
                f32x4 s = 0.f;
                s = MFMA(ah[rt][0], bh0, s);
                s = MFMA(ah[rt][1], bh1, s);
                s = MFMA(al[rt][0], bh0, s);
                s = MFMA(al[rt][1], bh1, s);
                s = MFMA(ah[rt][0], bl0, s);
                s = MFMA(ah[rt][1], bl1, s);
                const int prow = rbase + rt * 16 + quad * 4;
                #pragma unroll
                for (int e = 0; e < 4; ++e) {
                    float p = __expf(s[e] * 0.125f);
                    lp[rt][e] += p;
                    unsigned short h = f2b(p);
                    Ph[(prow + e) * 72 + kt * 16 + l15] = h;
                    Pl[(prow + e) * 72 + kt * 16 + l15] = f2b(p - b2f(h));
                }
            }
        }
        // ---- PV: acc^T[col][row] += (xh+xl) @ (Ph+Pl)  (no barrier: wave-local P) ----
        #pragma unroll
        for (int kh = 0; kh < 2; ++kh) {
            short8 axh[6], axl[6];
            #pragma unroll
            for (int ct = 0; ct < 6; ++ct) {
                long o = (long)(cb + ct * 16 + l15) * NN + k0 + kh * 32 + quad * 8;
                axh[ct] = *(const short8*)(xhb + o);
                axl[ct] = *(const short8*)(xlb + o);
            }
            #pragma unroll
            for (int nt = 0; nt < 2; ++nt) {
                int po = (rbase + nt * 16 + l15) * 72 + kh * 32 + quad * 8;
                short8 pbh = *(const short8*)&Ph[po];
                short8 pbl = *(const short8*)&Pl[po];
                #pragma unroll
                for (int ct = 0; ct < 6; ++ct) {
                    acc[ct][nt] = MFMA(axh[ct], pbh, acc[ct][nt]);
                    acc[ct][nt] = MFMA(axl[ct], pbh, acc[ct][nt]);
                    acc[ct][nt] = MFMA(axh[ct], pbl, acc[ct][nt]);
                }
            }
        }
    }

    // ---- softmax denominators (wave-local rows) ----
    #pragma unroll
    for (int rt = 0; rt < 2; ++rt)
        #pragma unroll
        for (int e = 0; e < 4; ++e) {
            float v = lp[rt][e];
            v += __shfl_xor(v, 1); v += __shfl_xor(v, 2);
            v += __shfl_xor(v, 4); v += __shfl_xor(v, 8);
            if (l15 == 0) lsum[rbase + rt * 16 + quad * 4 + e] = v;
        }
    __syncthreads();

    float* OTb = OT + (long)b * DD * NN;
    #pragma unroll
    for (int nt = 0; nt < 2; ++nt) {
        int row_l = rbase + nt * 16 + l15;
        int row = n0 + row_l;
        float linv = 1.f / lsum[row_l];
        float s1 = 0.f, s2 = 0.f;
        #pragma unroll
        for (int ct = 0; ct < 6; ++ct)
            #pragma unroll
            for (int e = 0; e < 4; ++e) {
                float v = acc[ct][nt][e] * linv;
                acc[ct][nt][e] = v;
                s1 += v; s2 += v * v;
            }
        s1 += __shfl_xor(s1, 16); s1 += __shfl_xor(s1, 32);
        s2 += __shfl_xor(s2, 16); s2 += __shfl_xor(s2, 32);
        #pragma unroll
        for (int ct = 0; ct < 6; ++ct)
            #pragma unroll
            for (int e = 0; e < 4; ++e)
                OTb[(long)(cb + ct * 16 + quad * 4 + e) * NN + row] = acc[ct][nt][e];
        if (lane < 16) {
            atomicAdd(&stats[((long)b * NN + row) * 2 + 0], s1);
            atomicAdd(&stats[((long)b * NN + row) * 2 + 1], s2);
        }
    }
}

// ---------- LN apply (mid layers): O^T fp32 -> split-bf16 xT ------------------------
__global__ __launch_bounds__(256) void lncvt_mid_kernel(
        const float* __restrict__ OT, const float* __restrict__ stats,
        const float* __restrict__ gamma, const float* __restrict__ beta,
        unsigned short* __restrict__ xTh, unsigned short* __restrict__ xTl) {
    int t = threadIdx.x;
    int n = blockIdx.x * 64 + (t & 63);
    int b = blockIdx.z;
    int c0 = blockIdx.y * 192 + (t >> 6);
    float s1 = stats[((long)b * NN + n) * 2 + 0];
    float s2 = stats[((long)b * NN + n) * 2 + 1];
    float mu = s1 * (1.f / 768.f);
    float rs = rsqrtf(s2 * (1.f / 768.f) - mu * mu + EPSF);
    const float* OTb = OT + (long)b * DD * NN;
    #pragma unroll 4
    for (int i = 0; i < 48; ++i) {
        int c = c0 + i * 4;
        float o = OTb[(long)c * NN + n];
        float y = (o - mu) * rs * gamma[c] + beta[c];
        unsigned short h = f2b(y);
        long idx = ((long)b * DD + c) * NN + n;
        xTh[idx] = h;
        xTl[idx] = f2b(y - b2f(h));
    }
}

// ---------- LN apply (final): O^T fp32 -> out fp32 [B][N][D] via LDS transpose ------
__global__ __launch_bounds__(256) void lncvt_final_kernel(
        const float* __restrict__ OT, const float* __restrict__ stats,
        const float* __restrict__ gamma, const float* __restrict__ beta,
        float* __restrict__ out) {
    __shared__ float T[64][65];
    int t = threadIdx.x;
    int nl = t & 63, cw = t >> 6;
    int b = blockIdx.y, n0 = blockIdx.x * 64;
    int n = n0 + nl;
    float s1 = stats[((long)b * NN + n) * 2 + 0];
    float s2 = stats[((long)b * NN + n) * 2 + 1];
    float mu = s1 * (1.f / 768.f);
    float rs = rsqrtf(s2 * (1.f / 768.f) - mu * mu + EPSF);
    const float* OTb = OT + (long)b * DD * NN;
    float* ob = out + (long)b * NN * DD;
    int row_l = t >> 2, seg = t & 3;
    for (int ct = 0; ct < 12; ++ct) {
        #pragma unroll
        for (int i = 0; i < 16; ++i) {
            int cl = cw + i * 4;
            int c = ct * 64 + cl;
            float o = OTb[(long)c * NN + n];
            T[nl][cl] = (o - mu) * rs * gamma[c] + beta[c];
        }
        __syncthreads();
        #pragma unroll
        for (int i = 0; i < 4; ++i) {
            int cl = seg * 16 + i * 4;
            float4 v = *(const float4*)&T[row_l][cl];
            *(float4*)&ob[(long)(n0 + row_l) * DD + ct * 64 + cl] = v;
        }
        __syncthreads();
    }
}

extern "C" void kernel_launch(void* const* d_in, const int* in_sizes, int n_in,
                              void* d_out, int out_size, void* d_ws, size_t ws_size,
                              hipStream_t stream) {
    (void)in_sizes; (void)n_in; (void)out_size; (void)ws_size;
    const float* x     = (const float*)d_in[0];
    const float* Wq    = (const float*)d_in[1];
    const float* bq    = (const float*)d_in[2];
    const float* gamma = (const float*)d_in[3];
    const float* beta  = (const float*)d_in[4];
    float* out = (float*)d_out;

    char* p = (char*)d_ws;
    const size_t szXT = (size_t)BB * DD * NN * 2;          // 28.3 MB
    unsigned short* xTh = (unsigned short*)p; p += szXT;
    unsigned short* xTl = (unsigned short*)p; p += szXT;
    float* OT           = (float*)p;          p += (size_t)BB * DD * NN * 4;   // 56.6 MB
    unsigned short* qh  = (unsigned short*)p; p += (size_t)BB * NN * DM * 2;
    unsigned short* ql  = (unsigned short*)p; p += (size_t)BB * NN * DM * 2;
    float* stats        = (float*)p;          p += (size_t)BB * NN * 2 * 4;
    unsigned short* Wth = (unsigned short*)p; p += (size_t)DM * DD * 2;
    unsigned short* Wtl = (unsigned short*)p; p += (size_t)DM * DD * 2;

    cvt_kernel<<<dim3(NN / 64, DD / 64, BB), 256, 0, stream>>>(x, xTh, xTl);
    wqcvt_kernel<<<dim3(DD * DM / 256), 256, 0, stream>>>(Wq, Wth, Wtl);

    for (int layer = 0; layer < 3; ++layer) {
        proj_kernel<<<dim3(NN / 64, BB), 256, 0, stream>>>(Wth, Wtl, xTh, xTl, bq, qh, ql);
        zstats_kernel<<<dim3(BB * NN * 2 / 256), 256, 0, stream>>>(stats);
        attn_kernel<<<dim3(18 * 64), 256, 0, stream>>>(qh, ql, xTh, xTl, OT, stats);
        if (layer < 2)
            lncvt_mid_kernel<<<dim3(NN / 64, 4, BB), 256, 0, stream>>>(OT, stats, gamma, beta, xTh, xTl);
        else
            lncvt_final_kernel<<<dim3(NN / 64, BB), 256, 0, stream>>>(OT, stats, gamma, beta, out);
    }
}

// Round 5
// 1947.453 us; speedup vs baseline: 5.3227x; 1.5431x over previous
//
#include <hip/hip_runtime.h>
#include <math.h>

#define BB 8
#define NN 2304
#define DD 768
#define DM 64
#define EPSF 1e-5f

typedef __attribute__((ext_vector_type(8))) short short8;   // 8 x bf16 bits
typedef __attribute__((ext_vector_type(4))) short short4v;  // 4 x bf16 bits (8 B)
typedef __attribute__((ext_vector_type(4))) float f32x4;

static __device__ __forceinline__ unsigned short f2b(float f) {
    unsigned u = __float_as_uint(f);
    unsigned r = u + 0x7FFFu + ((u >> 16) & 1u);
    return (unsigned short)(r >> 16);
}
static __device__ __forceinline__ float b2f(unsigned short h) {
    return __uint_as_float(((unsigned)h) << 16);
}
#define MFMA(a, b, c) __builtin_amdgcn_mfma_f32_16x16x32_bf16((a), (b), (c), 0, 0, 0)

// 8-byte-aligned LDS load/store of 8 bf16 (stride-68 rows are only 8B aligned)
static __device__ __forceinline__ short8 ld8(const unsigned short* p) {
    short4v a = *(const short4v*)p;
    short4v b = *(const short4v*)(p + 4);
    return __builtin_shufflevector(a, b, 0, 1, 2, 3, 4, 5, 6, 7);
}
static __device__ __forceinline__ void st8(unsigned short* p, short8 v) {
    *(short4v*)p = __builtin_shufflevector(v, v, 0, 1, 2, 3);
    *(short4v*)(p + 4) = __builtin_shufflevector(v, v, 4, 5, 6, 7);
}

// ---------- layer-0: fp32 x [B][N][D] -> split-bf16 transposed xT_hi/lo [B][D][N] ----
__global__ __launch_bounds__(256) void cvt_kernel(const float* __restrict__ xf,
                                                  unsigned short* __restrict__ xTh,
                                                  unsigned short* __restrict__ xTl) {
    __shared__ __align__(16) unsigned short Th[64][72];
    __shared__ __align__(16) unsigned short Tl[64][72];
    int t = threadIdx.x;
    int b = blockIdx.z;
    int n0 = blockIdx.x * 64, c0 = blockIdx.y * 64;
    int rr = t >> 4, cc = (t & 15) * 4;
    #pragma unroll
    for (int i = 0; i < 4; ++i) {
        int r = rr + i * 16;
        long idx = ((long)b * NN + n0 + r) * DD + c0 + cc;
        float4 v = *(const float4*)&xf[idx];
        unsigned short h0 = f2b(v.x), h1 = f2b(v.y), h2 = f2b(v.z), h3 = f2b(v.w);
        Th[cc + 0][r] = h0; Th[cc + 1][r] = h1; Th[cc + 2][r] = h2; Th[cc + 3][r] = h3;
        Tl[cc + 0][r] = f2b(v.x - b2f(h0));
        Tl[cc + 1][r] = f2b(v.y - b2f(h1));
        Tl[cc + 2][r] = f2b(v.z - b2f(h2));
        Tl[cc + 3][r] = f2b(v.w - b2f(h3));
    }
    __syncthreads();
    #pragma unroll
    for (int i = 0; i < 4; ++i) {
        int c = rr + i * 16;
        long idx = ((long)b * DD + c0 + c) * NN + n0 + cc;
        *(ushort4*)&xTh[idx] = *(const ushort4*)&Th[c][cc];
        *(ushort4*)&xTl[idx] = *(const ushort4*)&Tl[c][cc];
    }
}

// ---------- Wq fp32 [768][64] -> transposed split bf16 Wt_hi/lo [64][768] ----------
__global__ __launch_bounds__(256) void wqcvt_kernel(const float* __restrict__ Wq,
                                                    unsigned short* __restrict__ Wth,
                                                    unsigned short* __restrict__ Wtl) {
    int t = blockIdx.x * 256 + threadIdx.x;   // t < 768*64
    int d = t >> 6, m = t & 63;
    float v = Wq[t];
    unsigned short h = f2b(v);
    Wth[m * DD + d] = h;
    Wtl[m * DD + d] = f2b(v - b2f(h));
}

__global__ __launch_bounds__(256) void zstats_kernel(float* __restrict__ stats) {
    stats[blockIdx.x * 256 + threadIdx.x] = 0.f;
}

// ---------- MFMA q-projection (unchanged from R4; not the bottleneck) --------------
__global__ __launch_bounds__(256) void proj_kernel(
        const unsigned short* __restrict__ Wth, const unsigned short* __restrict__ Wtl,
        const unsigned short* __restrict__ xTh, const unsigned short* __restrict__ xTl,
        const float* __restrict__ bq,
        unsigned short* __restrict__ qh, unsigned short* __restrict__ ql) {
    int t = threadIdx.x;
    int w = t >> 6, lane = t & 63, quad = lane >> 4, l15 = lane & 15;
    int n0 = blockIdx.x * 64, b = blockIdx.y;
    const unsigned short* xhb = xTh + (long)b * DD * NN;
    const unsigned short* xlb = xTl + (long)b * DD * NN;

    f32x4 accQ[4];
    #pragma unroll
    for (int nt = 0; nt < 4; ++nt) accQ[nt] = 0.f;

    for (int d0 = 0; d0 < DD; d0 += 32) {
        short8 ah = *(const short8*)&Wth[(w * 16 + l15) * DD + d0 + quad * 8];
        short8 al = *(const short8*)&Wtl[(w * 16 + l15) * DD + d0 + quad * 8];
        #pragma unroll
        for (int nt = 0; nt < 4; ++nt) {
            int row = n0 + nt * 16 + l15;
            short8 bh, bl;
            #pragma unroll
            for (int j = 0; j < 8; ++j) {
                long o = (long)(d0 + quad * 8 + j) * NN + row;
                bh[j] = (short)xhb[o];
                bl[j] = (short)xlb[o];
            }
            accQ[nt] = MFMA(ah, bh, accQ[nt]);
            accQ[nt] = MFMA(al, bh, accQ[nt]);
            accQ[nt] = MFMA(ah, bl, accQ[nt]);
        }
    }
    #pragma unroll
    for (int nt = 0; nt < 4; ++nt) {
        int row = n0 + nt * 16 + l15;
        #pragma unroll
        for (int e = 0; e < 4; ++e) {
            int qm = w * 16 + quad * 4 + e;
            float v = accQ[nt][e] + bq[qm];
            unsigned short h = f2b(v);
            long o = ((long)b * NN + row) * DM + qm;
            qh[o] = h;
            ql[o] = f2b(v - b2f(h));
        }
    }
}

// ---------- flash attention: LDS-staged x, pipelined prefetch, wave-local P --------
// grid 1152; blockIdx%8 = batch. Block: 128 q-rows x 96 cols; wave w rows [w*32,+32).
__global__ __launch_bounds__(256) void attn_kernel(
        const unsigned short* __restrict__ qhp, const unsigned short* __restrict__ qlp,
        const unsigned short* __restrict__ xTh, const unsigned short* __restrict__ xTl,
        float* __restrict__ OT, float* __restrict__ stats) {
    __shared__ __align__(16) unsigned short XH[96 * 68];   // x-tile hi [col][key], pad 68
    __shared__ __align__(16) unsigned short XL[96 * 68];
    __shared__ __align__(16) unsigned short PH[128 * 68];  // P hi [qrow][key]
    __shared__ __align__(16) unsigned short PL[128 * 68];
    __shared__ float lsum[128];

    const int t = threadIdx.x;
    const int w = t >> 6, lane = t & 63, quad = lane >> 4, l15 = lane & 15;
    const int bx = blockIdx.x;
    const int combo = bx & 63, rt_idx = bx >> 6;
    const int b = combo & 7, g = combo >> 3;
    const int n0 = rt_idx * 128;
    const int rbase = w * 32;
    const int cb = g * 96;

    const unsigned short* qhb = qhp + (long)b * NN * DM;
    const unsigned short* qlb = qlp + (long)b * NN * DM;
    const unsigned short* xhb = xTh + (long)b * DD * NN;
    const unsigned short* xlb = xTl + (long)b * DD * NN;

    // loop-invariant S A-frags (this wave's 32 query rows)
    short8 ah[2][2], al[2][2];
    #pragma unroll
    for (int rt = 0; rt < 2; ++rt)
        #pragma unroll
        for (int kc = 0; kc < 2; ++kc) {
            long o = (long)(n0 + rbase + rt * 16 + l15) * DM + kc * 32 + quad * 8;
            ah[rt][kc] = *(const short8*)(qhb + o);
            al[rt][kc] = *(const short8*)(qlb + o);
        }

    float lp[2][4];
    #pragma unroll
    for (int rt = 0; rt < 2; ++rt)
        #pragma unroll
        for (int e = 0; e < 4; ++e) lp[rt][e] = 0.f;

    f32x4 acc[6][2];
    #pragma unroll
    for (int ct = 0; ct < 6; ++ct) { acc[ct][0] = 0.f; acc[ct][1] = 0.f; }

    // --- prefetch registers for the x-tile (24 KB / 256 thr = 3x16B per split) ---
    short8 xrh[3], xrl[3];
    #pragma unroll
    for (int i = 0; i < 3; ++i) {
        int slot = i * 256 + t, row = slot >> 3, seg = slot & 7;
        long gidx = (long)(cb + row) * NN + seg * 8;   // k0 = 0
        xrh[i] = *(const short8*)(xhb + gidx);
        xrl[i] = *(const short8*)(xlb + gidx);
    }

    for (int k0 = 0; k0 < NN; k0 += 64) {
        __syncthreads();   // prev iter's consumers done; LDS x-tile free
        #pragma unroll
        for (int i = 0; i < 3; ++i) {
            int slot = i * 256 + t, row = slot >> 3, seg = slot & 7;
            st8(&XH[row * 68 + seg * 8], xrh[i]);
            st8(&XL[row * 68 + seg * 8], xrl[i]);
        }
        __syncthreads();   // x-tile ready
        // issue next tile's loads now; consumed at next iter's st8 (vmcnt there)
        {
            int kn = k0 + 64; if (kn >= NN) kn = 0;
            #pragma unroll
            for (int i = 0; i < 3; ++i) {
                int slot = i * 256 + t, row = slot >> 3, seg = slot & 7;
                long gidx = (long)(cb + row) * NN + kn + seg * 8;
                xrh[i] = *(const short8*)(xhb + gidx);
                xrl[i] = *(const short8*)(xlb + gidx);
            }
        }

        // ---- S phase: q B-frags from global (L1-shared across waves/blocks) ----
        #pragma unroll
        for (int kt = 0; kt < 4; ++kt) {
            long o = (long)(k0 + kt * 16 + l15) * DM + quad * 8;
            short8 bh0 = *(const short8*)(qhb + o);
            short8 bh1 = *(const short8*)(qhb + o + 32);
            short8 bl0 = *(const short8*)(qlb + o);
            short8 bl1 = *(const short8*)(qlb + o + 32);
            #pragma unroll
            for (int rt = 0; rt < 2; ++rt) {
                f32x4 s = 0.f;
                s = MFMA(ah[rt][0], bh0, s);
                s = MFMA(ah[rt][1], bh1, s);
                s = MFMA(al[rt][0], bh0, s);
                s = MFMA(al[rt][1], bh1, s);
                s = MFMA(ah[rt][0], bl0, s);
                s = MFMA(ah[rt][1], bl1, s);
                const int prow = rbase + rt * 16 + quad * 4;
                #pragma unroll
                for (int e = 0; e < 4; ++e) {
                    float p = __expf(s[e] * 0.125f);
                    lp[rt][e] += p;
                    unsigned u = __float_as_uint(p);
                    float r = p - __uint_as_float(u & 0xFFFF0000u);
                    PH[(prow + e) * 68 + kt * 16 + l15] = (unsigned short)(u >> 16);
                    PL[(prow + e) * 68 + kt * 16 + l15] =
                        (unsigned short)(__float_as_uint(r) >> 16);
                }
            }
        }
        // ---- PV phase: A-frags from LDS x-tile, B-frags from wave-local P ----
        #pragma unroll
        for (int kh = 0; kh < 2; ++kh) {
            short8 pbh0 = ld8(&PH[(rbase + l15) * 68 + kh * 32 + quad * 8]);
            short8 pbl0 = ld8(&PL[(rbase + l15) * 68 + kh * 32 + quad * 8]);
            short8 pbh1 = ld8(&PH[(rbase + 16 + l15) * 68 + kh * 32 + quad * 8]);
            short8 pbl1 = ld8(&PL[(rbase + 16 + l15) * 68 + kh * 32 + quad * 8]);
            #pragma unroll
            for (int ct = 0; ct < 6; ++ct) {
                short8 axh = ld8(&XH[(ct * 16 + l15) * 68 + kh * 32 + quad * 8]);
                short8 axl = ld8(&XL[(ct * 16 + l15) * 68 + kh * 32 + quad * 8]);
                acc[ct][0] = MFMA(axh, pbh0, acc[ct][0]);
                acc[ct][0] = MFMA(axl, pbh0, acc[ct][0]);
                acc[ct][0] = MFMA(axh, pbl0, acc[ct][0]);
                acc[ct][1] = MFMA(axh, pbh1, acc[ct][1]);
                acc[ct][1] = MFMA(axl, pbh1, acc[ct][1]);
                acc[ct][1] = MFMA(axh, pbl1, acc[ct][1]);
            }
        }
    }

    // ---- softmax denominators ----
    #pragma unroll
    for (int rt = 0; rt < 2; ++rt)
        #pragma unroll
        for (int e = 0; e < 4; ++e) {
            float v = lp[rt][e];
            v += __shfl_xor(v, 1); v += __shfl_xor(v, 2);
            v += __shfl_xor(v, 4); v += __shfl_xor(v, 8);
            if (l15 == 0) lsum[rbase + rt * 16 + quad * 4 + e] = v;
        }
    __syncthreads();

    float* OTb = OT + (long)b * DD * NN;
    #pragma unroll
    for (int nt = 0; nt < 2; ++nt) {
        int row_l = rbase + nt * 16 + l15;
        int row = n0 + row_l;
        float linv = 1.f / lsum[row_l];
        float s1 = 0.f, s2 = 0.f;
        #pragma unroll
        for (int ct = 0; ct < 6; ++ct)
            #pragma unroll
            for (int e = 0; e < 4; ++e) {
                float v = acc[ct][nt][e] * linv;
                acc[ct][nt][e] = v;
                s1 += v; s2 += v * v;
            }
        s1 += __shfl_xor(s1, 16); s1 += __shfl_xor(s1, 32);
        s2 += __shfl_xor(s2, 16); s2 += __shfl_xor(s2, 32);
        #pragma unroll
        for (int ct = 0; ct < 6; ++ct)
            #pragma unroll
            for (int e = 0; e < 4; ++e)
                OTb[(long)(cb + ct * 16 + quad * 4 + e) * NN + row] = acc[ct][nt][e];
        if (lane < 16) {
            atomicAdd(&stats[((long)b * NN + row) * 2 + 0], s1);
            atomicAdd(&stats[((long)b * NN + row) * 2 + 1], s2);
        }
    }
}

// ---------- LN apply (mid layers): O^T fp32 -> split-bf16 xT ------------------------
__global__ __launch_bounds__(256) void lncvt_mid_kernel(
        const float* __restrict__ OT, const float* __restrict__ stats,
        const float* __restrict__ gamma, const float* __restrict__ beta,
        unsigned short* __restrict__ xTh, unsigned short* __restrict__ xTl) {
    int t = threadIdx.x;
    int n = blockIdx.x * 64 + (t & 63);
    int b = blockIdx.z;
    int c0 = blockIdx.y * 192 + (t >> 6);
    float s1 = stats[((long)b * NN + n) * 2 + 0];
    float s2 = stats[((long)b * NN + n) * 2 + 1];
    float mu = s1 * (1.f / 768.f);
    float rs = rsqrtf(s2 * (1.f / 768.f) - mu * mu + EPSF);
    const float* OTb = OT + (long)b * DD * NN;
    #pragma unroll 4
    for (int i = 0; i < 48; ++i) {
        int c = c0 + i * 4;
        float o = OTb[(long)c * NN + n];
        float y = (o - mu) * rs * gamma[c] + beta[c];
        unsigned short h = f2b(y);
        long idx = ((long)b * DD + c) * NN + n;
        xTh[idx] = h;
        xTl[idx] = f2b(y - b2f(h));
    }
}

// ---------- LN apply (final): O^T fp32 -> out fp32 [B][N][D] via LDS transpose ------
__global__ __launch_bounds__(256) void lncvt_final_kernel(
        const float* __restrict__ OT, const float* __restrict__ stats,
        const float* __restrict__ gamma, const float* __restrict__ beta,
        float* __restrict__ out) {
    __shared__ float T[64][65];
    int t = threadIdx.x;
    int nl = t & 63, cw = t >> 6;
    int b = blockIdx.y, n0 = blockIdx.x * 64;
    int n = n0 + nl;
    float s1 = stats[((long)b * NN + n) * 2 + 0];
    float s2 = stats[((long)b * NN + n) * 2 + 1];
    float mu = s1 * (1.f / 768.f);
    float rs = rsqrtf(s2 * (1.f / 768.f) - mu * mu + EPSF);
    const float* OTb = OT + (long)b * DD * NN;
    float* ob = out + (long)b * NN * DD;
    int row_l = t >> 2, seg = t & 3;
    for (int ct = 0; ct < 12; ++ct) {
        #pragma unroll
        for (int i = 0; i < 16; ++i) {
            int cl = cw + i * 4;
            int c = ct * 64 + cl;
            float o = OTb[(long)c * NN + n];
            T[nl][cl] = (o - mu) * rs * gamma[c] + beta[c];
        }
        __syncthreads();
        #pragma unroll
        for (int i = 0; i < 4; ++i) {
            int cl = seg * 16 + i * 4;
            float4 v = *(const float4*)&T[row_l][cl];
            *(float4*)&ob[(long)(n0 + row_l) * DD + ct * 64 + cl] = v;
        }
        __syncthreads();
    }
}

extern "C" void kernel_launch(void* const* d_in, const int* in_sizes, int n_in,
                              void* d_out, int out_size, void* d_ws, size_t ws_size,
                              hipStream_t stream) {
    (void)in_sizes; (void)n_in; (void)out_size; (void)ws_size;
    const float* x     = (const float*)d_in[0];
    const float* Wq    = (const float*)d_in[1];
    const float* bq    = (const float*)d_in[2];
    const float* gamma = (const float*)d_in[3];
    const float* beta  = (const float*)d_in[4];
    float* out = (float*)d_out;

    char* p = (char*)d_ws;
    const size_t szXT = (size_t)BB * DD * NN * 2;          // 28.3 MB
    unsigned short* xTh = (unsigned short*)p; p += szXT;
    unsigned short* xTl = (unsigned short*)p; p += szXT;
    float* OT           = (float*)p;          p += (size_t)BB * DD * NN * 4;   // 56.6 MB
    unsigned short* qh  = (unsigned short*)p; p += (size_t)BB * NN * DM * 2;
    unsigned short* ql  = (unsigned short*)p; p += (size_t)BB * NN * DM * 2;
    float* stats        = (float*)p;          p += (size_t)BB * NN * 2 * 4;
    unsigned short* Wth = (unsigned short*)p; p += (size_t)DM * DD * 2;
    unsigned short* Wtl = (unsigned short*)p; p += (size_t)DM * DD * 2;

    cvt_kernel<<<dim3(NN / 64, DD / 64, BB), 256, 0, stream>>>(x, xTh, xTl);
    wqcvt_kernel<<<dim3(DD * DM / 256), 256, 0, stream>>>(Wq, Wth, Wtl);

    for (int layer = 0; layer < 3; ++layer) {
        proj_kernel<<<dim3(NN / 64, BB), 256, 0, stream>>>(Wth, Wtl, xTh, xTl, bq, qh, ql);
        zstats_kernel<<<dim3(BB * NN * 2 / 256), 256, 0, stream>>>(stats);
        attn_kernel<<<dim3(18 * 64), 256, 0, stream>>>(qh, ql, xTh, xTl, OT, stats);
        if (layer < 2)
            lncvt_mid_kernel<<<dim3(NN / 64, 4, BB), 256, 0, stream>>>(OT, stats, gamma, beta, xTh, xTl);
        else
            lncvt_final_kernel<<<dim3(NN / 64, BB), 256, 0, stream>>>(OT, stats, gamma, beta, out);
    }
}